// Round 7
// baseline (294.954 us; speedup 1.0000x reference)
//
#include <hip/hip_runtime.h>
#include <hip/hip_bf16.h>
#include <math.h>

#define HEADS   4
#define HIDDEN  256
#define FIN     128
#define NGRAPH  256
#define WPB     4    // waves (=nodes) per block in k_agg
#define HISTB   512  // hist blocks appended to gemm grid
#define PCHUNK  64   // nodes per block in k_poolp

using frag_ab = __attribute__((ext_vector_type(8))) short;   // 8 bf16 (4 VGPRs)
using frag_cd = __attribute__((ext_vector_type(4))) float;   // 4 fp32

__device__ __forceinline__ float bf2f(unsigned short u) {
  union { unsigned int i; float f; } v; v.i = ((unsigned int)u) << 16; return v.f;
}
__device__ __forceinline__ unsigned short f2bf(float f) {
  union { float f; unsigned int i; } v; v.f = f;
  unsigned int b = v.i;
  b += 0x7FFFu + ((b >> 16) & 1u);   // round-to-nearest-even
  return (unsigned short)(b >> 16);
}

// ---------------- prep: W (fp32 [128][256]) -> bf16 MFMA-B-fragment order ----------------
__global__ __launch_bounds__(256) void k_prep(const float* __restrict__ W,
                                              unsigned short* __restrict__ Bf)
{
  int id = blockIdx.x * 256 + threadIdx.x;      // 0..4095
  if (id >= 16 * 4 * 64) return;
  int l = id & 63, ks = (id >> 6) & 3, nfg = id >> 8;
  int col = nfg * 16 + (l & 15);
  int k0  = ks * 32 + (l >> 4) * 8;
  unsigned short v[8];
  #pragma unroll
  for (int j = 0; j < 8; ++j) v[j] = f2bf(W[(k0 + j) * HIDDEN + col]);
  *(uint4*)(Bf + (size_t)id * 8) = *(const uint4*)v;
}

// ---------------- MFMA GEMM (+ edge histogram fused as trailing blocks) ----------------
__global__ __launch_bounds__(256) void k_gemmhist(
    const float* __restrict__ x, const unsigned short* __restrict__ Bf,
    const float* __restrict__ att_s, const float* __restrict__ att_d,
    unsigned short* __restrict__ h16, float* __restrict__ a_src, float* __restrict__ a_dst,
    const int* __restrict__ ei, int* __restrict__ count,
    int nNodes, int E, int gemmBlocks)
{
  __shared__ unsigned short As[32 * FIN];       // 8 KB, XOR-swizzled
  const int t = threadIdx.x;

  if (blockIdx.x >= gemmBlocks) {               // ---- histogram part ----
    int i = (blockIdx.x - gemmBlocks) * 256 + t;
    int stride = HISTB * 256;
    for (int e = i; e < E; e += stride) atomicAdd(&count[ei[E + e]], 1);
    return;                                     // self loops handled in scan (+1)
  }

  const int n0 = blockIdx.x * 32;

  // ---- stage x tile (fp32 -> bf16) into LDS with (row&7)<<4 byte-XOR swizzle ----
  {
    const int row = t >> 3;                     // 0..31
    const int g   = n0 + row;
    const int c0  = (t & 7) * 16;               // float offset in row
    float4 f0, f1, f2, f3;
    if (g < nNodes) {
      const float* xr = x + (size_t)g * FIN + c0;
      f0 = *(const float4*)(xr + 0);  f1 = *(const float4*)(xr + 4);
      f2 = *(const float4*)(xr + 8);  f3 = *(const float4*)(xr + 12);
    } else {
      f0 = f1 = f2 = f3 = make_float4(0.f, 0.f, 0.f, 0.f);
    }
    unsigned short u[16];
    u[0]=f2bf(f0.x); u[1]=f2bf(f0.y); u[2]=f2bf(f0.z); u[3]=f2bf(f0.w);
    u[4]=f2bf(f1.x); u[5]=f2bf(f1.y); u[6]=f2bf(f1.z); u[7]=f2bf(f1.w);
    u[8]=f2bf(f2.x); u[9]=f2bf(f2.y); u[10]=f2bf(f2.z); u[11]=f2bf(f2.w);
    u[12]=f2bf(f3.x); u[13]=f2bf(f3.y); u[14]=f2bf(f3.z); u[15]=f2bf(f3.w);
    const int sw = (row & 7) << 4;
    char* base = (char*)As + row * 256;
    *(uint4*)(base + (((t & 7) * 32)      ^ sw)) = *(const uint4*)(u + 0);
    *(uint4*)(base + (((t & 7) * 32 + 16) ^ sw)) = *(const uint4*)(u + 8);
  }
  __syncthreads();

  const int w    = t >> 6;                      // wave == head
  const int l    = t & 63;
  const int lrow = l & 15;

  frag_ab bfr[4][4];                            // [nf][ks]
  #pragma unroll
  for (int nf = 0; nf < 4; ++nf)
    #pragma unroll
    for (int ks = 0; ks < 4; ++ks)
      bfr[nf][ks] = *(const frag_ab*)(Bf + (size_t)(((w * 4 + nf) * 4 + ks) * 64 + l) * 8);

  frag_ab afr[2][4];                            // [mf][ks]
  const int lsw = (lrow & 7) << 4;
  #pragma unroll
  for (int mf = 0; mf < 2; ++mf)
    #pragma unroll
    for (int ks = 0; ks < 4; ++ks) {
      int byte = (mf * 16 + lrow) * 256 + ((ks * 64 + (l >> 4) * 16) ^ lsw);
      afr[mf][ks] = *(const frag_ab*)((const char*)As + byte);
    }

  frag_cd acc[2][4];
  #pragma unroll
  for (int mf = 0; mf < 2; ++mf)
    #pragma unroll
    for (int nf = 0; nf < 4; ++nf)
      acc[mf][nf] = (frag_cd){0.f, 0.f, 0.f, 0.f};
  #pragma unroll
  for (int ks = 0; ks < 4; ++ks)
    #pragma unroll
    for (int mf = 0; mf < 2; ++mf)
      #pragma unroll
      for (int nf = 0; nf < 4; ++nf)
        acc[mf][nf] = __builtin_amdgcn_mfma_f32_16x16x32_bf16(
            afr[mf][ks], bfr[nf][ks], acc[mf][nf], 0, 0, 0);

  float asw[4], adw[4];
  #pragma unroll
  for (int nf = 0; nf < 4; ++nf) {
    asw[nf] = att_s[w * 64 + nf * 16 + lrow];
    adw[nf] = att_d[w * 64 + nf * 16 + lrow];
  }

  #pragma unroll
  for (int mf = 0; mf < 2; ++mf) {
    #pragma unroll
    for (int r = 0; r < 4; ++r) {
      const int rowg = n0 + mf * 16 + (l >> 4) * 4 + r;
      if (rowg < nNodes) {
        #pragma unroll
        for (int nf = 0; nf < 4; ++nf)
          h16[(size_t)rowg * HIDDEN + w * 64 + nf * 16 + lrow] = f2bf(acc[mf][nf][r]);
      }
      float ss = 0.f, sd = 0.f;
      #pragma unroll
      for (int nf = 0; nf < 4; ++nf) {
        ss = fmaf(acc[mf][nf][r], asw[nf], ss);
        sd = fmaf(acc[mf][nf][r], adw[nf], sd);
      }
      #pragma unroll
      for (int off2 = 1; off2 <= 8; off2 <<= 1) {
        ss += __shfl_xor(ss, off2, 64);
        sd += __shfl_xor(sd, off2, 64);
      }
      if (lrow == 0 && rowg < nNodes) {
        a_src[rowg * HEADS + w] = ss;
        a_dst[rowg * HEADS + w] = sd;
      }
    }
  }
}

// ---------------- single-kernel exclusive scan of (cnt[i]+1) ----------------
// block b computes its global base by directly summing all preceding counts.
__global__ __launch_bounds__(256) void k_scan(const int* __restrict__ cnt,
                                              int* __restrict__ offs,
                                              int* __restrict__ cursor,
                                              int n, int total)
{
  const int t = threadIdx.x, b = blockIdx.x;
  // base = sum_{j < b*256} (cnt[j]+1); b*256 <= n always here
  int partial = 0;
  for (int j = t; j < b * 256; j += 256) partial += cnt[j];
  #pragma unroll
  for (int off2 = 32; off2; off2 >>= 1) partial += __shfl_xor(partial, off2, 64);
  __shared__ int bs4[4];
  if ((t & 63) == 0) bs4[t >> 6] = partial;
  __syncthreads();
  const int base = bs4[0] + bs4[1] + bs4[2] + bs4[3] + b * 256;  // +1 per preceding node

  const int i = b * 256 + t;
  const int v = (i < n) ? cnt[i] + 1 : 0;   // +1 = self loop
  int sc = v;
  #pragma unroll
  for (int d2 = 1; d2 < 64; d2 <<= 1) {
    int u = __shfl_up(sc, d2, 64);
    if ((t & 63) >= d2) sc += u;
  }
  __shared__ int wsum[4];
  if ((t & 63) == 63) wsum[t >> 6] = sc;
  __syncthreads();
  int wb = 0;
  for (int w = 0; w < (t >> 6); ++w) wb += wsum[w];
  const int excl = base + wb + sc - v;
  if (i < n) { offs[i] = excl; cursor[i] = excl; }
  if (i == 0) offs[n] = total;
}

// ---------------- scatter: src index + precomputed softmax weights into CSR slots ----------------
__global__ __launch_bounds__(256) void k_scatter(
    const int* __restrict__ ei,
    const float4* __restrict__ a_src4, const float4* __restrict__ a_dst4,
    int* __restrict__ cursor,
    int* __restrict__ ssrc, float4* __restrict__ see, int E, int N)
{
  int e = blockIdx.x * 256 + threadIdx.x;
  int tot = E + N;
  if (e >= tot) return;
  int s, d;
  if (e < E) { s = ei[e]; d = ei[E + e]; }
  else       { s = e - E; d = s; }        // self loop
  float4 as = a_src4[s];                  // 800KB arrays: L2-resident
  float4 ad = a_dst4[d];
  float4 w; float v;
  v = as.x + ad.x; v = v > 0.f ? v : 0.2f * v; w.x = __expf(v);
  v = as.y + ad.y; v = v > 0.f ? v : 0.2f * v; w.y = __expf(v);
  v = as.z + ad.z; v = v > 0.f ? v : 0.2f * v; w.z = __expf(v);
  v = as.w + ad.w; v = v > 0.f ? v : 0.2f * v; w.w = __expf(v);
  int pos = atomicAdd(&cursor[d], 1);
  ssrc[pos] = s;
  see[pos] = w;
}

// ---------------- aggregation: one WAVE per node; weights precomputed ----------------
// lane covers columns [4*lane, 4*lane+4); head = lane>>4.
__global__ __launch_bounds__(256) void k_agg(
    const unsigned short* __restrict__ h16, const int* __restrict__ offs,
    const int* __restrict__ ssrc, const float* __restrict__ see,
    const float* __restrict__ bias,
    unsigned short* __restrict__ outn, int N)
{
  const int wid0 = blockIdx.x * WPB + (threadIdx.x >> 6);
  if (wid0 >= N) return;
  const int wid  = __builtin_amdgcn_readfirstlane(wid0);   // wave-uniform -> s_loads
  const int lane = threadIdx.x & 63;
  const int head = lane >> 4;
  const int col  = lane << 2;

  const int beg = offs[wid], end = offs[wid + 1];

  float4 acc = make_float4(0.f, 0.f, 0.f, 0.f);
  float den = 0.f;
  int k = beg;

  for (; k + 16 <= end; k += 16) {
    int s[16];
    #pragma unroll
    for (int j = 0; j < 16; ++j) s[j] = ssrc[k + j];          // uniform -> s_load
    float w[16];
    #pragma unroll
    for (int j = 0; j < 16; ++j) w[j] = see[(size_t)(k + j) * 4 + head];  // indep of s
    ushort4 hv[16];
    #pragma unroll
    for (int j = 0; j < 16; ++j)
      hv[j] = *(const ushort4*)(h16 + (size_t)s[j] * HIDDEN + col);
    #pragma unroll
    for (int j = 0; j < 16; ++j) {
      den += w[j];
      acc.x = fmaf(bf2f(hv[j].x), w[j], acc.x);
      acc.y = fmaf(bf2f(hv[j].y), w[j], acc.y);
      acc.z = fmaf(bf2f(hv[j].z), w[j], acc.z);
      acc.w = fmaf(bf2f(hv[j].w), w[j], acc.w);
    }
  }
  for (; k + 4 <= end; k += 4) {
    int s[4];
    #pragma unroll
    for (int j = 0; j < 4; ++j) s[j] = ssrc[k + j];
    float w[4];
    #pragma unroll
    for (int j = 0; j < 4; ++j) w[j] = see[(size_t)(k + j) * 4 + head];
    ushort4 hv[4];
    #pragma unroll
    for (int j = 0; j < 4; ++j)
      hv[j] = *(const ushort4*)(h16 + (size_t)s[j] * HIDDEN + col);
    #pragma unroll
    for (int j = 0; j < 4; ++j) {
      den += w[j];
      acc.x = fmaf(bf2f(hv[j].x), w[j], acc.x);
      acc.y = fmaf(bf2f(hv[j].y), w[j], acc.y);
      acc.z = fmaf(bf2f(hv[j].z), w[j], acc.z);
      acc.w = fmaf(bf2f(hv[j].w), w[j], acc.w);
    }
  }
  for (; k < end; ++k) {
    int s = ssrc[k];
    float w = see[(size_t)k * 4 + head];
    ushort4 hv = *(const ushort4*)(h16 + (size_t)s * HIDDEN + col);
    den += w;
    acc.x = fmaf(bf2f(hv.x), w, acc.x); acc.y = fmaf(bf2f(hv.y), w, acc.y);
    acc.z = fmaf(bf2f(hv.z), w, acc.z); acc.w = fmaf(bf2f(hv.w), w, acc.w);
  }

  const float inv = 1.f / den;          // den > 0 guaranteed by self loop
  float4 bv = *(const float4*)&bias[col];
  float4 o;
  o.x = fmaf(acc.x, inv, bv.x); o.x = o.x > 0.f ? o.x : expm1f(o.x);
  o.y = fmaf(acc.y, inv, bv.y); o.y = o.y > 0.f ? o.y : expm1f(o.y);
  o.z = fmaf(acc.z, inv, bv.z); o.z = o.z > 0.f ? o.z : expm1f(o.z);
  o.w = fmaf(acc.w, inv, bv.w); o.w = o.w > 0.f ? o.w : expm1f(o.w);

  ushort4 ov;
  ov.x = f2bf(o.x); ov.y = f2bf(o.y); ov.z = f2bf(o.z); ov.w = f2bf(o.w);
  *(ushort4*)(outn + (size_t)wid * HIDDEN + col) = ov;
}

// ---------------- parallel pooling: run-length partial sums, atomic flush ----------------
__global__ __launch_bounds__(256) void k_poolp(
    const unsigned short* __restrict__ outn, const int* __restrict__ batch,
    float* __restrict__ pooled, float* __restrict__ cntg, int N)
{
  const int t = threadIdx.x;
  const int n0 = blockIdx.x * PCHUNK;
  if (n0 >= N) return;
  const int n1 = (n0 + PCHUNK < N) ? n0 + PCHUNK : N;

  int cur = batch[n0];
  float run = 0.f;
  int runlen = 0;
  int n = n0;
  for (; n + 4 <= n1; n += 4) {
    unsigned short r0 = outn[(size_t)(n + 0) * HIDDEN + t];
    unsigned short r1 = outn[(size_t)(n + 1) * HIDDEN + t];
    unsigned short r2 = outn[(size_t)(n + 2) * HIDDEN + t];
    unsigned short r3 = outn[(size_t)(n + 3) * HIDDEN + t];
    int g0 = batch[n + 0], g3 = batch[n + 3];
    if (g0 == cur && g3 == cur) {
      run += (bf2f(r0) + bf2f(r1)) + (bf2f(r2) + bf2f(r3));
      runlen += 4;
    } else {
      unsigned short rr[4] = {r0, r1, r2, r3};
      #pragma unroll
      for (int j = 0; j < 4; ++j) {
        int g = batch[n + j];
        if (g != cur) {
          atomicAdd(&pooled[cur * HIDDEN + t], run);
          if (t == 0) atomicAdd(&cntg[cur], (float)runlen);
          run = 0.f; runlen = 0; cur = g;
        }
        run += bf2f(rr[j]); runlen++;
      }
    }
  }
  for (; n < n1; ++n) {
    int g = batch[n];
    if (g != cur) {
      atomicAdd(&pooled[cur * HIDDEN + t], run);
      if (t == 0) atomicAdd(&cntg[cur], (float)runlen);
      run = 0.f; runlen = 0; cur = g;
    }
    run += bf2f(outn[(size_t)n * HIDDEN + t]); runlen++;
  }
  atomicAdd(&pooled[cur * HIDDEN + t], run);
  if (t == 0) atomicAdd(&cntg[cur], (float)runlen);
}

// ---------------- final: mean + FC from pooled sums ----------------
__global__ __launch_bounds__(64) void k_fc(
    const float* __restrict__ pooled, const float* __restrict__ cntg,
    const float* __restrict__ fc_w, const float* __restrict__ fc_b, float* __restrict__ out)
{
  int g = blockIdx.x, l = threadIdx.x;
  float acc = 0.f;
  #pragma unroll
  for (int j = 0; j < HIDDEN / 64; ++j) acc += pooled[g * HIDDEN + j * 64 + l] * fc_w[j * 64 + l];
  #pragma unroll
  for (int off2 = 32; off2; off2 >>= 1) acc += __shfl_xor(acc, off2, 64);
  if (l == 0) out[g] = acc / fmaxf(cntg[g], 1.0f) + fc_b[0];
}

extern "C" void kernel_launch(void* const* d_in, const int* in_sizes, int n_in,
                              void* d_out, int out_size, void* d_ws, size_t ws_size,
                              hipStream_t stream)
{
  const float* x     = (const float*)d_in[0];
  const int*   ei    = (const int*)  d_in[1];   // [2,E] flat: [0..E)=src, [E..2E)=dst
  /* d_in[2] edge_attr: unused by reference */
  const int*   batch = (const int*)  d_in[3];
  const float* W     = (const float*)d_in[4];
  const float* att_s = (const float*)d_in[5];
  const float* att_d = (const float*)d_in[6];
  const float* bias  = (const float*)d_in[7];
  const float* fc_w  = (const float*)d_in[8];
  const float* fc_b  = (const float*)d_in[9];
  float* out = (float*)d_out;

  const int N   = in_sizes[0] / FIN;
  const int E   = in_sizes[1] / 2;
  const int TOT = E + N;

  char* p = (char*)d_ws;
  size_t o = 0;
  auto alloc = [&](size_t bytes) -> void* {
    void* r = p + o;
    o = (o + bytes + 255) & ~(size_t)255;
    return r;
  };
  // zero-init region first: one memset covers [count | pooled | cntg]
  int*   count  = (int*)  alloc((size_t)N * sizeof(int));
  float* pooled = (float*)alloc((size_t)NGRAPH * HIDDEN * sizeof(float));
  float* cntg   = (float*)alloc((size_t)NGRAPH * sizeof(float));
  size_t zeroBytes = o;
  unsigned short* h16 = (unsigned short*)alloc((size_t)N * HIDDEN * sizeof(unsigned short));
  unsigned short* Bf  = (unsigned short*)alloc((size_t)FIN * HIDDEN * sizeof(unsigned short));
  float* a_src  = (float*)alloc((size_t)N * 4 * sizeof(float));
  float* a_dst  = (float*)alloc((size_t)N * 4 * sizeof(float));
  int*   offs   = (int*)  alloc((size_t)(N + 1) * sizeof(int));
  int*   cursor = (int*)  alloc((size_t)N * sizeof(int));
  int*   ssrc   = (int*)  alloc((size_t)TOT * sizeof(int));
  float* see    = (float*)alloc((size_t)TOT * 4 * sizeof(float));
  unsigned short* outn = (unsigned short*)alloc((size_t)N * HIDDEN * sizeof(unsigned short));
  (void)n_in; (void)out_size; (void)ws_size;

  (void)hipMemsetAsync(d_ws, 0, zeroBytes, stream);

  const int gemmBlocks = (N + 31) / 32;
  hipLaunchKernelGGL(k_prep, dim3(16), dim3(256), 0, stream, W, Bf);
  hipLaunchKernelGGL(k_gemmhist, dim3(gemmBlocks + HISTB), dim3(256), 0, stream,
                     x, Bf, att_s, att_d, h16, a_src, a_dst, ei, count, N, E, gemmBlocks);
  const int sb = (N + 255) / 256;
  hipLaunchKernelGGL(k_scan, dim3(sb), dim3(256), 0, stream, count, offs, cursor, N, TOT);
  hipLaunchKernelGGL(k_scatter, dim3((TOT + 255) / 256), dim3(256), 0, stream,
                     ei, (const float4*)a_src, (const float4*)a_dst, cursor, ssrc,
                     (float4*)see, E, N);
  hipLaunchKernelGGL(k_agg, dim3((N + WPB - 1) / WPB), dim3(256), 0, stream,
                     h16, offs, ssrc, see, bias, outn, N);
  hipLaunchKernelGGL(k_poolp, dim3((N + PCHUNK - 1) / PCHUNK), dim3(256), 0, stream,
                     outn, batch, pooled, cntg, N);
  hipLaunchKernelGGL(k_fc, dim3(NGRAPH), dim3(64), 0, stream,
                     pooled, cntg, fc_w, fc_b, out);
}